// Round 1
// baseline (301.847 us; speedup 1.0000x reference)
//
#include <hip/hip_runtime.h>
#include <type_traits>

// ---------------------------------------------------------------------------
// MultiHeadAttention fused pipeline for MI355X (gfx950)
// x[B,S,E] @ w_qkv -> split QKV -> RoPE -> causal GQA flash attention -> @ w_dense
// B=2 S=2048 E=2048 H=16 KVH=4 D=128
// R9: attn restructure for LDS-read amortization. Old: 64-row q-tiles, 16
//     q-rows/wave -> each wave reads full Ks+VTs (32KB) per chunk for 16 rows
//     of MFMA; LDS reads ~47% of kernel at 2 waves/SIMD. New: 128-row q-tiles,
//     32 q-rows/wave (2x16 mh sub-tiles) -> same kf/vf reads feed 2x MFMAs.
//     QK^T operands swapped (mfma(K,Q)): lane's 4 acc regs walk kv -> P pairs
//     packed with v_cvt_pk_bf16_f32, 16x ds_write_b32 (was 32x b16 + manual
//     RNE). Ps[128][64] XOR-swizzled; LDS = 80KB exactly (2 blocks/CU).
//     Grid stays 512 blocks; t = b ? 15-bx : bx pairs t with 15-t on the same
//     CU (blocks i and i+256 co-resident) -> uniform 34 chunk-units/CU.
// ---------------------------------------------------------------------------

typedef __attribute__((ext_vector_type(8))) short short8;
typedef __attribute__((ext_vector_type(4))) float floatx4;
typedef __attribute__((ext_vector_type(4))) unsigned short ushort4v;

constexpr int NH    = 16;
constexpr int NKV   = 4;
constexpr int HD    = 128;
constexpr int SEQ   = 2048;
constexpr int EMB   = 2048;
constexpr int NBATCH = 2;
constexpr int MROWS = NBATCH * SEQ;          // 4096
constexpr int NQKV  = (NH + 2 * NKV) * HD;   // 3072

__device__ __forceinline__ unsigned short f2b(float f) {
  union { float f; unsigned u; } v; v.f = f;
  unsigned u = v.u + 0x7FFFu + ((v.u >> 16) & 1u);   // RNE
  return (unsigned short)(u >> 16);
}
__device__ __forceinline__ float b2f(unsigned short h) {
  union { unsigned u; float f; } v; v.u = (unsigned)h << 16;
  return v.f;
}

// async global->LDS DMA, 16B per lane; lds dest = uniform base + lane*16
__device__ __forceinline__ void gload_lds16(const unsigned short* g,
                                            unsigned short* lds) {
  __builtin_amdgcn_global_load_lds(
      (const __attribute__((address_space(1))) unsigned int*)g,
      (__attribute__((address_space(3))) unsigned int*)lds, 16, 0, 0);
}

// --------------------------- fp32 -> bf16 cast ------------------------------
__global__ void cvt_f32_bf16(const float* __restrict__ in,
                             unsigned short* __restrict__ out, int n) {
  int i = (blockIdx.x * 256 + threadIdx.x) * 4;
  if (i + 3 < n) {
    floatx4 v = *(const floatx4*)(in + i);
    ushort4v o = { f2b(v[0]), f2b(v[1]), f2b(v[2]), f2b(v[3]) };
    *(ushort4v*)(out + i) = o;
  }
}

// ---------- fp32 [R][C] -> bf16 [C][R] transpose, both weights in one -------
__global__ void transpose_cvt_dual(const float* __restrict__ wqkv,
                                   unsigned short* __restrict__ oqkv,
                                   const float* __restrict__ wd,
                                   unsigned short* __restrict__ od) {
  const int z = blockIdx.z;
  const float* in = z ? wd : wqkv;
  unsigned short* out = z ? od : oqkv;
  const int R = EMB;                       // both weights have 2048 rows
  const int C = z ? EMB : NQKV;
  int c0 = blockIdx.x * 32, r0 = blockIdx.y * 32;
  if (c0 >= C) return;
  __shared__ float t[32][33];
  int tx = threadIdx.x & 31, ty = threadIdx.x >> 5;  // ty 0..7
#pragma unroll
  for (int i = 0; i < 32; i += 8)
    t[ty + i][tx] = in[(long)(r0 + ty + i) * C + (c0 + tx)];
  __syncthreads();
#pragma unroll
  for (int i = 0; i < 32; i += 8)
    out[(long)(c0 + ty + i) * R + (r0 + tx)] = f2b(t[tx][ty + i]);
}

// ------------------------- RoPE (in-place, Q and K) -------------------------
// slot bh<32: Q [2*16 heads], scale=qscale; else K [2*4 heads], scale=1.
__global__ void rope_kernel(unsigned short* __restrict__ Qb,
                            unsigned short* __restrict__ Kb, float qscale) {
  int idx = blockIdx.x * 256 + threadIdx.x;
  int i = idx & 63;
  int s = (idx >> 6) & (SEQ - 1);
  int bh = idx >> 17;                       // SEQ*64 = 1<<17
  unsigned short* p;
  float scale;
  if (bh < NBATCH * NH) { p = Qb + ((long)bh * SEQ + s) * HD; scale = qscale; }
  else { p = Kb + ((long)(bh - NBATCH * NH) * SEQ + s) * HD; scale = 1.0f; }
  float e = -(float)i * (2.0f * 13.287712379549449f / 128.0f);
  float ang = (float)s * exp2f(e);
  float sn, c;
  sincosf(ang, &sn, &c);
  float x1 = b2f(p[i]), x2 = b2f(p[i + 64]);
  p[i]      = f2b((x1 * c - x2 * sn) * scale);
  p[i + 64] = f2b((x2 * c + x1 * sn) * scale);
}

// ------------------------------- GEMM (B^T) ---------------------------------
// C[M][N] = A[M][K](bf16) * BT[N][K](bf16)^T.  128x128 tile, 4 waves of 64x64.
// Unpadded LDS with XOR-swizzled 16B blocks (conflict-free fragment reads),
// global_load_lds width-16 staging, 3 blocks/CU.
// MODE 0: Q/K tiles -> LDS-repack epilogue, bf16 16B stores head-major;
//         V tiles  -> direct transposed ushort4 stores into VT[d][s].
// MODE 1: fp32 dense store to outF.
constexpr int BM = 128, BN = 128, BK = 64;

template <int MODE>
__global__ __launch_bounds__(256, 3) void gemm_bt(
    const unsigned short* __restrict__ A,
    const unsigned short* __restrict__ BT,
    int Mdim, int Ndim, int Kdim,
    float* __restrict__ outF,
    unsigned short* __restrict__ Qb,
    unsigned short* __restrict__ Kb,
    unsigned short* __restrict__ Vt) {
  __shared__ __align__(16) unsigned short smem[BM * BK + BN * BK];  // 32 KB
  unsigned short (*As)[BK] = (unsigned short (*)[BK])smem;
  unsigned short (*Bs)[BK] = (unsigned short (*)[BK])(smem + BM * BK);
  const int tid = threadIdx.x;
  const int bm = blockIdx.y * BM;
  const int bn = blockIdx.x * BN;
  const int wave = tid >> 6, lane = tid & 63;
  const int l = lane & 15, q = lane >> 4;
  const int l7 = l & 7;
  const int wm = (wave >> 1) * 64, wn = (wave & 1) * 64;

  floatx4 acc[4][4] = {};

  // DMA staging: one issue = 64 lanes x 16B = 1KB = 8 rows of 64 shorts.
  // Lane (srow=lane>>3, bp=lane&7) lands at phys block bp of row srow;
  // it FETCHES logical block bp^srow, so logical bl sits at phys bl^(row&7).
  const int srow = lane >> 3;                    // 0..7
  const int scol = ((lane & 7) ^ srow) * 8;      // swizzled source col (shorts)
  const unsigned short* Arow = A + (long)bm * Kdim;
  const unsigned short* Brow = BT + (long)bn * Kdim;

  for (int k0 = 0; k0 < Kdim; k0 += BK) {
#pragma unroll
    for (int i = 0; i < 4; ++i) {
      const int r0 = wave * 32 + i * 8;
      gload_lds16(Arow + (long)(r0 + srow) * Kdim + k0 + scol, &As[r0][0]);
      gload_lds16(Brow + (long)(r0 + srow) * Kdim + k0 + scol, &Bs[r0][0]);
    }
    __syncthreads();
#pragma unroll
    for (int kk = 0; kk < 2; ++kk) {
      short8 af[4], bfr[4];
#pragma unroll
      for (int mi = 0; mi < 4; ++mi)
        af[mi] = *(const short8*)&As[wm + mi * 16 + l][((kk * 4 + q) ^ l7) * 8];
#pragma unroll
      for (int ni = 0; ni < 4; ++ni)
        bfr[ni] = *(const short8*)&Bs[wn + ni * 16 + l][((kk * 4 + q) ^ l7) * 8];
#pragma unroll
      for (int mi = 0; mi < 4; ++mi)
#pragma unroll
        for (int ni = 0; ni < 4; ++ni)
          acc[mi][ni] = __builtin_amdgcn_mfma_f32_16x16x32_bf16(
              af[mi], bfr[ni], acc[mi][ni], 0, 0, 0);
    }
    __syncthreads();
  }

  if constexpr (MODE == 1) {
#pragma unroll
    for (int mi = 0; mi < 4; ++mi) {
      const int rowbase = bm + wm + mi * 16 + q * 4;
#pragma unroll
      for (int ni = 0; ni < 4; ++ni) {
        const int col = bn + wn + ni * 16 + l;
#pragma unroll
        for (int r = 0; r < 4; ++r)
          outF[(long)(rowbase + r) * Ndim + col] = acc[mi][ni][r];
      }
    }
  } else if (bn >= (NH + NKV) * HD) {
    // ---- V tile: direct transposed stores (4 consecutive s per lane) ----
    const int hh = (bn - (NH + NKV) * HD) >> 7;
#pragma unroll
    for (int mi = 0; mi < 4; ++mi) {
      const int m0 = bm + wm + mi * 16 + q * 4;
      const int bb = m0 >> 11, s = m0 & (SEQ - 1);
      unsigned short* vtb = Vt + ((long)(bb * NKV + hh)) * HD * SEQ;
#pragma unroll
      for (int ni = 0; ni < 4; ++ni) {
        const int d = wn + ni * 16 + l;        // BN == HD
        ushort4v pv = { f2b(acc[mi][ni][0]), f2b(acc[mi][ni][1]),
                        f2b(acc[mi][ni][2]), f2b(acc[mi][ni][3]) };
        *(ushort4v*)(vtb + (long)d * SEQ + s) = pv;
      }
    }
  } else {
    // ---- Q/K tiles: repack through LDS (overlays As/Bs) ----
    // Ct[128][128] bf16, 16B-block col swizzle: blk_phys = blk ^ (row & 7).
    unsigned short (*Ct)[128] = (unsigned short (*)[128])smem;
#pragma unroll
    for (int mi = 0; mi < 4; ++mi)
#pragma unroll
      for (int ni = 0; ni < 4; ++ni)
#pragma unroll
        for (int r = 0; r < 4; ++r) {
          const int row = wm + mi * 16 + q * 4 + r;
          const int col = wn + ni * 16 + l;
          const int cs = ((((col >> 3) ^ row) & 7) | (col & 64 ? 8 : 0)) * 8 + (col & 7);
          Ct[row][cs] = f2b(acc[mi][ni][r]);
        }
    __syncthreads();
    const int row = tid >> 1, g = tid & 1;
    const int m = bm + row, bb = m >> 11, s = m & (SEQ - 1);
    unsigned short* dst;
    if (bn < NH * HD)
      dst = Qb + (((long)(bb * NH + (bn >> 7))) * SEQ + s) * HD;
    else
      dst = Kb + (((long)(bb * NKV + ((bn - NH * HD) >> 7))) * SEQ + s) * HD;
#pragma unroll
    for (int i = 0; i < 8; ++i) {
      const int blk = (g * 8) + (i ^ (row & 7));
      *(short8*)(dst + g * 64 + i * 8) = *(const short8*)&Ct[row][blk * 8];
    }
  }
}

// --------------------------- flash attention --------------------------------
// R9 structure: 128-row q-tiles, 4 waves x 32 q-rows (2 mh sub-tiles of 16).
// kf/vf LDS reads amortized over 2x MFMAs vs R8. Swapped QK^T: sf = mfma(K,Q)
// puts kv in the acc-reg axis -> P pairs packed via v_cvt_pk_bf16_f32 into
// b32 LDS writes. Ps[128][64] XOR-swizzled (same 8-block scheme as Ks/VTs).
// LDS: Ks 32K + VTs 32K + Ps 16K = 80KB = 2 blocks/CU exactly.
// Grid (16,16,2); t = b ? 15-bx : bx so the two co-resident blocks per CU
// (linear ids i, i+256) carry complementary tiles -> uniform 34 chunks/CU.
__global__ __launch_bounds__(256, 2) void attn_kernel(
    const unsigned short* __restrict__ Q,   // [B][NH][S][D], pre-scaled by 1/sqrt(d)*log2e
    const unsigned short* __restrict__ K,   // [B][NKV][S][D]
    const unsigned short* __restrict__ VT,  // [B][NKV][D][S]
    unsigned short* __restrict__ attn) {    // [B*S][NH*D]
  const int h = blockIdx.y, b = blockIdx.z;
  const int t = b ? (15 - (int)blockIdx.x) : (int)blockIdx.x;  // q-tile (128 rows)
  const int kvh = h >> 2;   // jnp.repeat: q head h uses kv head h/4
  const int tid = threadIdx.x;
  const int wave = tid >> 6, lane = tid & 63;
  const int l = lane & 15, q = lane >> 4;
  const int l7 = l & 7;
  const int wq = wave * 32;

  const unsigned short* Kh  = K  + ((long)(b * NKV + kvh)) * SEQ * HD;
  const unsigned short* VTh = VT + ((long)(b * NKV + kvh)) * HD * SEQ;

  __shared__ __align__(16) unsigned short Ks[2][64 * 128];    // 32 KB swizzled
  __shared__ __align__(16) unsigned short VTs[2][128 * 64];   // 32 KB swizzled
  __shared__ __align__(16) unsigned short Ps[128 * 64];       // 16 KB swizzled

  // per-lane DMA offsets (in shorts), computed once; base advances per chunk
  int koff[4], voff[4];
  {
    const int k_rl = lane >> 4, k_bp = lane & 15;
    const int v_rl = lane >> 3, v_bp = lane & 7;
#pragma unroll
    for (int j = 0; j < 4; ++j) {
      const int rk = (wave * 4 + j) * 4 + k_rl;
      koff[j] = rk * HD + (k_bp ^ (rk & 15)) * 8;
      const int rv = (wave * 4 + j) * 8 + v_rl;
      voff[j] = rv * SEQ + (v_bp ^ (rv & 7)) * 8;
    }
  }

  short8 onesf;
#pragma unroll
  for (int i = 0; i < 8; ++i) onesf[i] = (short)0x3F80;   // bf16 1.0

  auto stage = [&](int c, int buf) {
    const unsigned short* kc = Kh + c * (64 * HD);
    const unsigned short* vc = VTh + c * 64;
#pragma unroll
    for (int j = 0; j < 4; ++j)
      gload_lds16(kc + koff[j], &Ks[buf][(wave * 4 + j) * 4 * 128]);
#pragma unroll
    for (int j = 0; j < 4; ++j)
      gload_lds16(vc + voff[j], &VTs[buf][(wave * 4 + j) * 8 * 64]);
  };

  // ---- Q fragments: 32 rows per wave, resident for the whole block ----
  const unsigned short* Qh = Q + (((long)(b * NH + h)) * SEQ + t * 128) * HD;
  short8 qf[2][4];
#pragma unroll
  for (int mh = 0; mh < 2; ++mh)
#pragma unroll
    for (int kk = 0; kk < 4; ++kk)
      qf[mh][kk] = *(const short8*)(Qh + (long)(wq + mh * 16 + l) * HD + kk * 32 + q * 8);

  floatx4 o[2][9] = {};   // [mh][0..7]=O d-tiles, [8]=denominator (ones col)

  auto chunk_body = [&](auto masked, int cur, int kv0) {
    constexpr bool MASKED = decltype(masked)::value;
    // ---- S^T = K Q^T (64kv x 32q per wave); lane: kv=ni*16+q*4+r, q=l ----
    floatx4 sf[2][4] = {};
#pragma unroll
    for (int kk = 0; kk < 4; ++kk) {
      short8 kf[4];
#pragma unroll
      for (int ni = 0; ni < 4; ++ni)
        kf[ni] = *(const short8*)&Ks[cur][(ni * 16 + l) * 128 + (((kk * 4 + q) ^ l) * 8)];
#pragma unroll
      for (int mh = 0; mh < 2; ++mh)
#pragma unroll
        for (int ni = 0; ni < 4; ++ni)
          sf[mh][ni] = __builtin_amdgcn_mfma_f32_16x16x32_bf16(
              kf[ni], qf[mh][kk], sf[mh][ni], 0, 0, 0);
    }
    // ---- P = exp2(S) -> packed b32 LDS writes (kv pairs contiguous) ----
#pragma unroll
    for (int mh = 0; mh < 2; ++mh) {
      const int prow = wq + mh * 16 + l;
      const int qrow = t * 128 + prow;
#pragma unroll
      for (int ni = 0; ni < 4; ++ni) {
        if constexpr (MASKED) {
#pragma unroll
          for (int r = 0; r < 4; ++r)
            if (kv0 + ni * 16 + q * 4 + r > qrow) sf[mh][ni][r] = -3e38f;  // exp2 -> 0
        }
        float e0 = exp2f(sf[mh][ni][0]);
        float e1 = exp2f(sf[mh][ni][1]);
        float e2 = exp2f(sf[mh][ni][2]);
        float e3 = exp2f(sf[mh][ni][3]);
        unsigned u0, u1;
        asm("v_cvt_pk_bf16_f32 %0, %1, %2" : "=v"(u0) : "v"(e0), "v"(e1));
        asm("v_cvt_pk_bf16_f32 %0, %1, %2" : "=v"(u1) : "v"(e2), "v"(e3));
        const int base = prow * 64 + (((ni * 2 + (q >> 1)) ^ l7) * 8) + (q & 1) * 4;
        *(unsigned*)&Ps[base] = u0;
        *(unsigned*)&Ps[base + 2] = u1;
      }
    }
    // ---- O += P V ; o[mh][8] += P * ones (denominator) ----
#pragma unroll
    for (int kvk = 0; kvk < 2; ++kvk) {
      const int pb = ((kvk * 4 + q) ^ l7) * 8;
      short8 pf0 = *(const short8*)&Ps[(wq + l) * 64 + pb];
      short8 pf1 = *(const short8*)&Ps[(wq + 16 + l) * 64 + pb];
#pragma unroll
      for (int di = 0; di < 8; ++di) {
        short8 vf = *(const short8*)&VTs[cur][(di * 16 + l) * 64 + pb];
        o[0][di] = __builtin_amdgcn_mfma_f32_16x16x32_bf16(pf0, vf, o[0][di], 0, 0, 0);
        o[1][di] = __builtin_amdgcn_mfma_f32_16x16x32_bf16(pf1, vf, o[1][di], 0, 0, 0);
      }
      o[0][8] = __builtin_amdgcn_mfma_f32_16x16x32_bf16(pf0, onesf, o[0][8], 0, 0, 0);
      o[1][8] = __builtin_amdgcn_mfma_f32_16x16x32_bf16(pf1, onesf, o[1][8], 0, 0, 0);
    }
  };

  const int nc = 2 * t + 2;   // causal: kv up to 128t+127, Tk=64
  stage(0, 0);
  __syncthreads();

  int c = 0;
#pragma unroll 1
  for (; c < nc - 2; ++c) {
    stage(c + 1, (c & 1) ^ 1);
    chunk_body(std::false_type{}, c & 1, c * 64);
    __syncthreads();   // prefetch DMA drained; all reads of cur done
  }
  // last two chunks are masked (diagonal spans 128 q-rows = 2 kv-chunks)
  stage(c + 1, (c & 1) ^ 1);
  chunk_body(std::true_type{}, c & 1, c * 64);
  __syncthreads();
  ++c;
  chunk_body(std::true_type{}, c & 1, c * 64);
  __syncthreads();     // all waves done reading Ks/VTs before repack overwrite

  // ---- epilogue: repack O through (dead) Ks+VTs LDS, 16B coalesced stores ----
  unsigned short (*Ob)[136] = (unsigned short (*)[136])&Ks[0][0];  // 34.8 KB
#pragma unroll
  for (int mh = 0; mh < 2; ++mh)
#pragma unroll
    for (int r = 0; r < 4; ++r) {
      const float inv = 1.0f / o[mh][8][r];   // l (same value in every lane)
#pragma unroll
      for (int di = 0; di < 8; ++di)
        Ob[wq + mh * 16 + q * 4 + r][di * 16 + l] = f2b(o[mh][di][r] * inv);
    }
  __syncthreads();
  {
    const int row = tid >> 1, g = (tid & 1) * 64;
    const int s = t * 128 + row;
    unsigned short* dst = attn + ((long)(b * SEQ + s)) * (NH * HD) + h * HD + g;
#pragma unroll
    for (int j = 0; j < 8; ++j)
      *(short8*)(dst + j * 8) = *(const short8*)&Ob[row][g + j * 8];
  }
}

// ---------------------------------------------------------------------------
extern "C" void kernel_launch(void* const* d_in, const int* in_sizes, int n_in,
                              void* d_out, int out_size, void* d_ws, size_t ws_size,
                              hipStream_t stream) {
  const float* x       = (const float*)d_in[0];   // [2,2048,2048]
  const float* w_qkv   = (const float*)d_in[1];   // [2048,3072]
  const float* w_dense = (const float*)d_in[2];   // [2048,2048]
  float* out = (float*)d_out;                     // [2,2048,2048] fp32

  char* ws = (char*)d_ws;
  const size_t MB = 1024 * 1024;
  unsigned short* xb    = (unsigned short*)(ws);            // 16 MB (aliased as attn later)
  unsigned short* wqkvT = (unsigned short*)(ws + 16 * MB);  // 12 MB
  unsigned short* wdT   = (unsigned short*)(ws + 28 * MB);  //  8 MB
  unsigned short* Qb    = (unsigned short*)(ws + 36 * MB);  // 16 MB
  unsigned short* Kb    = (unsigned short*)(ws + 52 * MB);  //  4 MB
  unsigned short* VTb   = (unsigned short*)(ws + 56 * MB);  //  4 MB   (total 60 MB)
  unsigned short* attn  = xb;   // x no longer needed after qkv GEMM

  const float qscale = 0.08838834764831845f * 1.4426950408889634f; // 1/sqrt(128)*log2e

  cvt_f32_bf16<<<(MROWS * EMB) / (256 * 4), 256, 0, stream>>>(x, xb, MROWS * EMB);
  transpose_cvt_dual<<<dim3(NQKV / 32, EMB / 32, 2), 256, 0, stream>>>(
      w_qkv, wqkvT, w_dense, wdT);

  gemm_bt<0><<<dim3(NQKV / BN, MROWS / BM), 256, 0, stream>>>(
      xb, wqkvT, MROWS, NQKV, EMB, nullptr, Qb, Kb, VTb);

  rope_kernel<<<(NBATCH * (NH + NKV) * SEQ * 64) / 256, 256, 0, stream>>>(Qb, Kb, qscale);

  attn_kernel<<<dim3(16, NH, NBATCH), 256, 0, stream>>>(Qb, Kb, VTb, attn);

  gemm_bt<1><<<dim3(EMB / BN, MROWS / BM), 256, 0, stream>>>(
      attn, wdT, MROWS, EMB, NH * HD, out, nullptr, nullptr, nullptr);
}

// Round 2
// 283.032 us; speedup vs baseline: 1.0665x; 1.0665x over previous
//
#include <hip/hip_runtime.h>
#include <type_traits>

// ---------------------------------------------------------------------------
// MultiHeadAttention fused pipeline for MI355X (gfx950)
// x[B,S,E] @ w_qkv -> split QKV -> RoPE -> causal GQA flash attention -> @ w_dense
// B=2 S=2048 E=2048 H=16 KVH=4 D=128
// R10: register-resident P (no Ps LDS). PV's kv-sum is permutation-invariant:
//      with swapped QK^T, lane (l,q) holds P[kv=ni*16+q*4+r][qrow=l]; under
//      kv-permutation pi(32c2+8q+j) = 32c2+(j>=4)*16+4q+(j&3) the lane's own
//      cvt_pk'd accumulators ARE the PV A-fragment (4 u32 = short8). V is
//      stored pre-permuted in global (free bit-shuffle in gemm V-epilogue).
//      Removes 16 ds_write_b32 + 4 ds_read_b128 + P lgkm serialization per
//      chunk/wave; LDS 80KB->64KB restores 2 blocks/CU (R9 measured 13% occ
//      = 1 block/CU at 80KB).
// ---------------------------------------------------------------------------

typedef __attribute__((ext_vector_type(8))) short short8;
typedef __attribute__((ext_vector_type(4))) float floatx4;
typedef __attribute__((ext_vector_type(4))) unsigned short ushort4v;
typedef __attribute__((ext_vector_type(4))) unsigned int uint4v;

constexpr int NH    = 16;
constexpr int NKV   = 4;
constexpr int HD    = 128;
constexpr int SEQ   = 2048;
constexpr int EMB   = 2048;
constexpr int NBATCH = 2;
constexpr int MROWS = NBATCH * SEQ;          // 4096
constexpr int NQKV  = (NH + 2 * NKV) * HD;   // 3072

__device__ __forceinline__ unsigned short f2b(float f) {
  union { float f; unsigned u; } v; v.f = f;
  unsigned u = v.u + 0x7FFFu + ((v.u >> 16) & 1u);   // RNE
  return (unsigned short)(u >> 16);
}
__device__ __forceinline__ float b2f(unsigned short h) {
  union { unsigned u; float f; } v; v.u = (unsigned)h << 16;
  return v.f;
}

// async global->LDS DMA, 16B per lane; lds dest = uniform base + lane*16
__device__ __forceinline__ void gload_lds16(const unsigned short* g,
                                            unsigned short* lds) {
  __builtin_amdgcn_global_load_lds(
      (const __attribute__((address_space(1))) unsigned int*)g,
      (__attribute__((address_space(3))) unsigned int*)lds, 16, 0, 0);
}

// --------------------------- fp32 -> bf16 cast ------------------------------
__global__ void cvt_f32_bf16(const float* __restrict__ in,
                             unsigned short* __restrict__ out, int n) {
  int i = (blockIdx.x * 256 + threadIdx.x) * 4;
  if (i + 3 < n) {
    floatx4 v = *(const floatx4*)(in + i);
    ushort4v o = { f2b(v[0]), f2b(v[1]), f2b(v[2]), f2b(v[3]) };
    *(ushort4v*)(out + i) = o;
  }
}

// ---------- fp32 [R][C] -> bf16 [C][R] transpose, both weights in one -------
__global__ void transpose_cvt_dual(const float* __restrict__ wqkv,
                                   unsigned short* __restrict__ oqkv,
                                   const float* __restrict__ wd,
                                   unsigned short* __restrict__ od) {
  const int z = blockIdx.z;
  const float* in = z ? wd : wqkv;
  unsigned short* out = z ? od : oqkv;
  const int R = EMB;                       // both weights have 2048 rows
  const int C = z ? EMB : NQKV;
  int c0 = blockIdx.x * 32, r0 = blockIdx.y * 32;
  if (c0 >= C) return;
  __shared__ float t[32][33];
  int tx = threadIdx.x & 31, ty = threadIdx.x >> 5;  // ty 0..7
#pragma unroll
  for (int i = 0; i < 32; i += 8)
    t[ty + i][tx] = in[(long)(r0 + ty + i) * C + (c0 + tx)];
  __syncthreads();
#pragma unroll
  for (int i = 0; i < 32; i += 8)
    out[(long)(c0 + ty + i) * R + (r0 + tx)] = f2b(t[tx][ty + i]);
}

// ------------------------- RoPE (in-place, Q and K) -------------------------
// slot bh<32: Q [2*16 heads], scale=qscale; else K [2*4 heads], scale=1.
__global__ void rope_kernel(unsigned short* __restrict__ Qb,
                            unsigned short* __restrict__ Kb, float qscale) {
  int idx = blockIdx.x * 256 + threadIdx.x;
  int i = idx & 63;
  int s = (idx >> 6) & (SEQ - 1);
  int bh = idx >> 17;                       // SEQ*64 = 1<<17
  unsigned short* p;
  float scale;
  if (bh < NBATCH * NH) { p = Qb + ((long)bh * SEQ + s) * HD; scale = qscale; }
  else { p = Kb + ((long)(bh - NBATCH * NH) * SEQ + s) * HD; scale = 1.0f; }
  float e = -(float)i * (2.0f * 13.287712379549449f / 128.0f);
  float ang = (float)s * exp2f(e);
  float sn, c;
  sincosf(ang, &sn, &c);
  float x1 = b2f(p[i]), x2 = b2f(p[i + 64]);
  p[i]      = f2b((x1 * c - x2 * sn) * scale);
  p[i + 64] = f2b((x2 * c + x1 * sn) * scale);
}

// ------------------------------- GEMM (B^T) ---------------------------------
// C[M][N] = A[M][K](bf16) * BT[N][K](bf16)^T.  128x128 tile, 4 waves of 64x64.
// Unpadded LDS with XOR-swizzled 16B blocks (conflict-free fragment reads),
// global_load_lds width-16 staging, 3 blocks/CU.
// MODE 0: Q/K tiles -> LDS-repack epilogue, bf16 16B stores head-major;
//         V tiles  -> transposed ushort4 stores into VT[d][s] with the attn
//         kv-permutation applied to s%64 (see attn R10 note).
// MODE 1: fp32 dense store to outF.
constexpr int BM = 128, BN = 128, BK = 64;

template <int MODE>
__global__ __launch_bounds__(256, 3) void gemm_bt(
    const unsigned short* __restrict__ A,
    const unsigned short* __restrict__ BT,
    int Mdim, int Ndim, int Kdim,
    float* __restrict__ outF,
    unsigned short* __restrict__ Qb,
    unsigned short* __restrict__ Kb,
    unsigned short* __restrict__ Vt) {
  __shared__ __align__(16) unsigned short smem[BM * BK + BN * BK];  // 32 KB
  unsigned short (*As)[BK] = (unsigned short (*)[BK])smem;
  unsigned short (*Bs)[BK] = (unsigned short (*)[BK])(smem + BM * BK);
  const int tid = threadIdx.x;
  const int bm = blockIdx.y * BM;
  const int bn = blockIdx.x * BN;
  const int wave = tid >> 6, lane = tid & 63;
  const int l = lane & 15, q = lane >> 4;
  const int l7 = l & 7;
  const int wm = (wave >> 1) * 64, wn = (wave & 1) * 64;

  floatx4 acc[4][4] = {};

  // DMA staging: one issue = 64 lanes x 16B = 1KB = 8 rows of 64 shorts.
  // Lane (srow=lane>>3, bp=lane&7) lands at phys block bp of row srow;
  // it FETCHES logical block bp^srow, so logical bl sits at phys bl^(row&7).
  const int srow = lane >> 3;                    // 0..7
  const int scol = ((lane & 7) ^ srow) * 8;      // swizzled source col (shorts)
  const unsigned short* Arow = A + (long)bm * Kdim;
  const unsigned short* Brow = BT + (long)bn * Kdim;

  for (int k0 = 0; k0 < Kdim; k0 += BK) {
#pragma unroll
    for (int i = 0; i < 4; ++i) {
      const int r0 = wave * 32 + i * 8;
      gload_lds16(Arow + (long)(r0 + srow) * Kdim + k0 + scol, &As[r0][0]);
      gload_lds16(Brow + (long)(r0 + srow) * Kdim + k0 + scol, &Bs[r0][0]);
    }
    __syncthreads();
#pragma unroll
    for (int kk = 0; kk < 2; ++kk) {
      short8 af[4], bfr[4];
#pragma unroll
      for (int mi = 0; mi < 4; ++mi)
        af[mi] = *(const short8*)&As[wm + mi * 16 + l][((kk * 4 + q) ^ l7) * 8];
#pragma unroll
      for (int ni = 0; ni < 4; ++ni)
        bfr[ni] = *(const short8*)&Bs[wn + ni * 16 + l][((kk * 4 + q) ^ l7) * 8];
#pragma unroll
      for (int mi = 0; mi < 4; ++mi)
#pragma unroll
        for (int ni = 0; ni < 4; ++ni)
          acc[mi][ni] = __builtin_amdgcn_mfma_f32_16x16x32_bf16(
              af[mi], bfr[ni], acc[mi][ni], 0, 0, 0);
    }
    __syncthreads();
  }

  if constexpr (MODE == 1) {
#pragma unroll
    for (int mi = 0; mi < 4; ++mi) {
      const int rowbase = bm + wm + mi * 16 + q * 4;
#pragma unroll
      for (int ni = 0; ni < 4; ++ni) {
        const int col = bn + wn + ni * 16 + l;
#pragma unroll
        for (int r = 0; r < 4; ++r)
          outF[(long)(rowbase + r) * Ndim + col] = acc[mi][ni][r];
      }
    }
  } else if (bn >= (NH + NKV) * HD) {
    // ---- V tile: transposed stores, kv-permuted within each 64-s chunk ----
    // s%64 bits [5]=c2 [4]=u [3:2]=qq [1:0]=r  ->  p = [5]=c2 [4:3]=qq [2]=u [1:0]=r
    // so that attn's PV A-fragment (lane q holds kv-slots 8q..8q+7 = its own
    // QK accumulators ni=2c2+u, r) matches the B-fragment read from VT.
    const int hh = (bn - (NH + NKV) * HD) >> 7;
#pragma unroll
    for (int mi = 0; mi < 4; ++mi) {
      const int m0 = bm + wm + mi * 16 + q * 4;
      const int bb = m0 >> 11, s = m0 & (SEQ - 1);
      const int s6 = s & 63;                 // bits[1:0]=0 (q*4 aligned)
      const int p6 = (s6 & 32) | ((s6 & 12) << 1) | ((s6 & 16) >> 2);
      const int sp = (s & ~63) | p6;
      unsigned short* vtb = Vt + ((long)(bb * NKV + hh)) * HD * SEQ;
#pragma unroll
      for (int ni = 0; ni < 4; ++ni) {
        const int d = wn + ni * 16 + l;        // BN == HD
        ushort4v pv = { f2b(acc[mi][ni][0]), f2b(acc[mi][ni][1]),
                        f2b(acc[mi][ni][2]), f2b(acc[mi][ni][3]) };
        *(ushort4v*)(vtb + (long)d * SEQ + sp) = pv;
      }
    }
  } else {
    // ---- Q/K tiles: repack through LDS (overlays As/Bs) ----
    // Ct[128][128] bf16, 16B-block col swizzle: blk_phys = blk ^ (row & 7).
    unsigned short (*Ct)[128] = (unsigned short (*)[128])smem;
#pragma unroll
    for (int mi = 0; mi < 4; ++mi)
#pragma unroll
      for (int ni = 0; ni < 4; ++ni)
#pragma unroll
        for (int r = 0; r < 4; ++r) {
          const int row = wm + mi * 16 + q * 4 + r;
          const int col = wn + ni * 16 + l;
          const int cs = ((((col >> 3) ^ row) & 7) | (col & 64 ? 8 : 0)) * 8 + (col & 7);
          Ct[row][cs] = f2b(acc[mi][ni][r]);
        }
    __syncthreads();
    const int row = tid >> 1, g = tid & 1;
    const int m = bm + row, bb = m >> 11, s = m & (SEQ - 1);
    unsigned short* dst;
    if (bn < NH * HD)
      dst = Qb + (((long)(bb * NH + (bn >> 7))) * SEQ + s) * HD;
    else
      dst = Kb + (((long)(bb * NKV + ((bn - NH * HD) >> 7))) * SEQ + s) * HD;
#pragma unroll
    for (int i = 0; i < 8; ++i) {
      const int blk = (g * 8) + (i ^ (row & 7));
      *(short8*)(dst + g * 64 + i * 8) = *(const short8*)&Ct[row][blk * 8];
    }
  }
}

// --------------------------- flash attention --------------------------------
// R10 structure: 128-row q-tiles, 4 waves x 32 q-rows (2 mh sub-tiles of 16).
// Swapped QK^T (sf = mfma(K,Q)) -> lane holds P[kv=ni*16+q*4+r][qrow=l].
// P stays in registers: cvt_pk pairs -> 4 u32 = short8 = PV A-fragment under
// the kv-permutation baked into VT's global layout (see gemm V-epilogue).
// LDS: Ks 32K + VTs 32K = 64KB -> 2 blocks/CU.
// Grid (16,16,2); t = b ? 15-bx : bx so the two co-resident blocks per CU
// (linear ids i, i+256) carry complementary tiles -> uniform 34 chunks/CU.
__global__ __launch_bounds__(256, 2) void attn_kernel(
    const unsigned short* __restrict__ Q,   // [B][NH][S][D], pre-scaled by 1/sqrt(d)*log2e
    const unsigned short* __restrict__ K,   // [B][NKV][S][D]
    const unsigned short* __restrict__ VT,  // [B][NKV][D][S], kv-permuted per 64
    unsigned short* __restrict__ attn) {    // [B*S][NH*D]
  const int h = blockIdx.y, b = blockIdx.z;
  const int t = b ? (15 - (int)blockIdx.x) : (int)blockIdx.x;  // q-tile (128 rows)
  const int kvh = h >> 2;   // jnp.repeat: q head h uses kv head h/4
  const int tid = threadIdx.x;
  const int wave = tid >> 6, lane = tid & 63;
  const int l = lane & 15, q = lane >> 4;
  const int l7 = l & 7;
  const int wq = wave * 32;

  const unsigned short* Kh  = K  + ((long)(b * NKV + kvh)) * SEQ * HD;
  const unsigned short* VTh = VT + ((long)(b * NKV + kvh)) * HD * SEQ;

  __shared__ __align__(16) unsigned short smem[2 * 64 * 128 + 2 * 128 * 64]; // 64 KB
  unsigned short (*Ks)[64 * 128]  = (unsigned short (*)[64 * 128])smem;
  unsigned short (*VTs)[128 * 64] = (unsigned short (*)[128 * 64])(smem + 2 * 64 * 128);

  // per-lane DMA offsets (in shorts), computed once; base advances per chunk
  int koff[4], voff[4];
  {
    const int k_rl = lane >> 4, k_bp = lane & 15;
    const int v_rl = lane >> 3, v_bp = lane & 7;
#pragma unroll
    for (int j = 0; j < 4; ++j) {
      const int rk = (wave * 4 + j) * 4 + k_rl;
      koff[j] = rk * HD + (k_bp ^ (rk & 15)) * 8;
      const int rv = (wave * 4 + j) * 8 + v_rl;
      voff[j] = rv * SEQ + (v_bp ^ (rv & 7)) * 8;
    }
  }

  short8 onesf;
#pragma unroll
  for (int i = 0; i < 8; ++i) onesf[i] = (short)0x3F80;   // bf16 1.0

  auto stage = [&](int c, int buf) {
    const unsigned short* kc = Kh + c * (64 * HD);
    const unsigned short* vc = VTh + c * 64;
#pragma unroll
    for (int j = 0; j < 4; ++j)
      gload_lds16(kc + koff[j], &Ks[buf][(wave * 4 + j) * 4 * 128]);
#pragma unroll
    for (int j = 0; j < 4; ++j)
      gload_lds16(vc + voff[j], &VTs[buf][(wave * 4 + j) * 8 * 64]);
  };

  // ---- Q fragments: 32 rows per wave, resident for the whole block ----
  const unsigned short* Qh = Q + (((long)(b * NH + h)) * SEQ + t * 128) * HD;
  short8 qf[2][4];
#pragma unroll
  for (int mh = 0; mh < 2; ++mh)
#pragma unroll
    for (int kk = 0; kk < 4; ++kk)
      qf[mh][kk] = *(const short8*)(Qh + (long)(wq + mh * 16 + l) * HD + kk * 32 + q * 8);

  floatx4 o[2][9] = {};   // [mh][0..7]=O d-tiles, [8]=denominator (ones col)

  auto chunk_body = [&](auto masked, int cur, int kv0) {
    constexpr bool MASKED = decltype(masked)::value;
    // ---- S^T = K Q^T (64kv x 32q per wave); lane: kv=ni*16+q*4+r, q=l ----
    floatx4 sf[2][4] = {};
#pragma unroll
    for (int kk = 0; kk < 4; ++kk) {
      short8 kf[4];
#pragma unroll
      for (int ni = 0; ni < 4; ++ni)
        kf[ni] = *(const short8*)&Ks[cur][(ni * 16 + l) * 128 + (((kk * 4 + q) ^ l) * 8)];
#pragma unroll
      for (int mh = 0; mh < 2; ++mh)
#pragma unroll
        for (int ni = 0; ni < 4; ++ni)
          sf[mh][ni] = __builtin_amdgcn_mfma_f32_16x16x32_bf16(
              kf[ni], qf[mh][kk], sf[mh][ni], 0, 0, 0);
    }
    // ---- P = exp2(S), packed in-register: pf[mh][c2] = A-fragment ----
    short8 pf[2][2];
#pragma unroll
    for (int mh = 0; mh < 2; ++mh) {
      const int qrow = t * 128 + wq + mh * 16 + l;
      unsigned u[8];
#pragma unroll
      for (int ni = 0; ni < 4; ++ni) {
        if constexpr (MASKED) {
#pragma unroll
          for (int r = 0; r < 4; ++r)
            if (kv0 + ni * 16 + q * 4 + r > qrow) sf[mh][ni][r] = -3e38f;  // exp2 -> 0
        }
        float e0 = exp2f(sf[mh][ni][0]);
        float e1 = exp2f(sf[mh][ni][1]);
        float e2 = exp2f(sf[mh][ni][2]);
        float e3 = exp2f(sf[mh][ni][3]);
        asm("v_cvt_pk_bf16_f32 %0, %1, %2" : "=v"(u[ni * 2]) : "v"(e0), "v"(e1));
        asm("v_cvt_pk_bf16_f32 %0, %1, %2" : "=v"(u[ni * 2 + 1]) : "v"(e2), "v"(e3));
      }
      union { uint4v v; short8 s; } a0, a1;
      a0.v = (uint4v){u[0], u[1], u[2], u[3]};
      a1.v = (uint4v){u[4], u[5], u[6], u[7]};
      pf[mh][0] = a0.s;   // kv-slots: pi(8q+j) = q*4+(j&3) + (j>=4)*16
      pf[mh][1] = a1.s;   // + 32
    }
    // ---- O += P V ; o[mh][8] += P * ones (denominator) ----
#pragma unroll
    for (int c2 = 0; c2 < 2; ++c2) {
      const int pb = ((c2 * 4 + q) ^ l7) * 8;
#pragma unroll
      for (int di = 0; di < 8; ++di) {
        short8 vf = *(const short8*)&VTs[cur][(di * 16 + l) * 64 + pb];
        o[0][di] = __builtin_amdgcn_mfma_f32_16x16x32_bf16(pf[0][c2], vf, o[0][di], 0, 0, 0);
        o[1][di] = __builtin_amdgcn_mfma_f32_16x16x32_bf16(pf[1][c2], vf, o[1][di], 0, 0, 0);
      }
      o[0][8] = __builtin_amdgcn_mfma_f32_16x16x32_bf16(pf[0][c2], onesf, o[0][8], 0, 0, 0);
      o[1][8] = __builtin_amdgcn_mfma_f32_16x16x32_bf16(pf[1][c2], onesf, o[1][8], 0, 0, 0);
    }
  };

  const int nc = 2 * t + 2;   // causal: kv up to 128t+127, Tk=64
  stage(0, 0);
  __syncthreads();

  int c = 0;
#pragma unroll 1
  for (; c < nc - 2; ++c) {
    stage(c + 1, (c & 1) ^ 1);
    chunk_body(std::false_type{}, c & 1, c * 64);
    __syncthreads();   // prefetch DMA drained; all reads of cur done
  }
  // last two chunks are masked (diagonal spans 128 q-rows = 2 kv-chunks)
  stage(c + 1, (c & 1) ^ 1);
  chunk_body(std::true_type{}, c & 1, c * 64);
  __syncthreads();
  ++c;
  chunk_body(std::true_type{}, c & 1, c * 64);
  __syncthreads();     // all waves done reading Ks/VTs before repack overwrite

  // ---- epilogue: repack O through (dead) smem, 16B coalesced stores ----
  unsigned short (*Ob)[136] = (unsigned short (*)[136])smem;  // 34.8 KB < 64 KB
#pragma unroll
  for (int mh = 0; mh < 2; ++mh)
#pragma unroll
    for (int r = 0; r < 4; ++r) {
      const float inv = 1.0f / o[mh][8][r];   // l (same value in every lane)
#pragma unroll
      for (int di = 0; di < 8; ++di)
        Ob[wq + mh * 16 + q * 4 + r][di * 16 + l] = f2b(o[mh][di][r] * inv);
    }
  __syncthreads();
  {
    const int row = tid >> 1, g = (tid & 1) * 64;
    const int s = t * 128 + row;
    unsigned short* dst = attn + ((long)(b * SEQ + s)) * (NH * HD) + h * HD + g;
#pragma unroll
    for (int j = 0; j < 8; ++j)
      *(short8*)(dst + j * 8) = *(const short8*)&Ob[row][g + j * 8];
  }
}

// ---------------------------------------------------------------------------
extern "C" void kernel_launch(void* const* d_in, const int* in_sizes, int n_in,
                              void* d_out, int out_size, void* d_ws, size_t ws_size,
                              hipStream_t stream) {
  const float* x       = (const float*)d_in[0];   // [2,2048,2048]
  const float* w_qkv   = (const float*)d_in[1];   // [2048,3072]
  const float* w_dense = (const float*)d_in[2];   // [2048,2048]
  float* out = (float*)d_out;                     // [2,2048,2048] fp32

  char* ws = (char*)d_ws;
  const size_t MB = 1024 * 1024;
  unsigned short* xb    = (unsigned short*)(ws);            // 16 MB (aliased as attn later)
  unsigned short* wqkvT = (unsigned short*)(ws + 16 * MB);  // 12 MB
  unsigned short* wdT   = (unsigned short*)(ws + 28 * MB);  //  8 MB
  unsigned short* Qb    = (unsigned short*)(ws + 36 * MB);  // 16 MB
  unsigned short* Kb    = (unsigned short*)(ws + 52 * MB);  //  4 MB
  unsigned short* VTb   = (unsigned short*)(ws + 56 * MB);  //  4 MB   (total 60 MB)
  unsigned short* attn  = xb;   // x no longer needed after qkv GEMM

  const float qscale = 0.08838834764831845f * 1.4426950408889634f; // 1/sqrt(128)*log2e

  cvt_f32_bf16<<<(MROWS * EMB) / (256 * 4), 256, 0, stream>>>(x, xb, MROWS * EMB);
  transpose_cvt_dual<<<dim3(NQKV / 32, EMB / 32, 2), 256, 0, stream>>>(
      w_qkv, wqkvT, w_dense, wdT);

  gemm_bt<0><<<dim3(NQKV / BN, MROWS / BM), 256, 0, stream>>>(
      xb, wqkvT, MROWS, NQKV, EMB, nullptr, Qb, Kb, VTb);

  rope_kernel<<<(NBATCH * (NH + NKV) * SEQ * 64) / 256, 256, 0, stream>>>(Qb, Kb, qscale);

  attn_kernel<<<dim3(16, NH, NBATCH), 256, 0, stream>>>(Qb, Kb, VTb, attn);

  gemm_bt<1><<<dim3(EMB / BN, MROWS / BM), 256, 0, stream>>>(
      attn, wdT, MROWS, EMB, NH * HD, out, nullptr, nullptr, nullptr);
}